// Round 1
// baseline (749.179 us; speedup 1.0000x reference)
//
#include <hip/hip_runtime.h>
#include <hip/hip_bf16.h>

#define HID1 16
#define NHEAD1 12
#define F1 (HID1*NHEAD1)   // 192
#define HID2 8
#define NHEAD2 8
#define F2 (HID2*NHEAD2)   // 64
#define NUM_FEA 213
#define NEG_SLOPE 0.2f

// ---------------- CSR build ----------------

__global__ void deg_kernel(const int* __restrict__ ei, int* __restrict__ cnt, int E, int Etot) {
    int e = blockIdx.x * blockDim.x + threadIdx.x;
    if (e >= Etot) return;
    int d = (e < E) ? ei[E + e] : (e - E);
    atomicAdd(&cnt[d], 1);
}

__global__ void scan_kernel(const int* __restrict__ cnt, int* __restrict__ rowstart, int N) {
    __shared__ int carry;
    __shared__ int tmp[1024];
    int tid = threadIdx.x;
    if (tid == 0) carry = 0;
    __syncthreads();
    for (int base = 0; base < N; base += 1024) {
        int i = base + tid;
        int v = (i < N) ? cnt[i] : 0;
        tmp[tid] = v;
        __syncthreads();
        for (int off = 1; off < 1024; off <<= 1) {
            int add = (tid >= off) ? tmp[tid - off] : 0;
            __syncthreads();
            tmp[tid] += add;
            __syncthreads();
        }
        int incl = tmp[tid];
        int excl = carry + incl - v;
        if (i < N) rowstart[i] = excl;
        __syncthreads();
        if (tid == 1023) carry += incl;
        __syncthreads();
    }
    if (tid == 0) rowstart[N] = carry;
}

__global__ void fill_kernel(const int* __restrict__ ei, const int* __restrict__ rowstart,
                            int* __restrict__ cnt2, int* __restrict__ esrc, int E, int Etot) {
    int e = blockIdx.x * blockDim.x + threadIdx.x;
    if (e >= Etot) return;
    int s, d;
    if (e < E) { s = ei[e]; d = ei[E + e]; } else { s = e - E; d = s; }
    int pos = atomicAdd(&cnt2[d], 1);
    esrc[rowstart[d] + pos] = s;
}

// ---------------- tiled f32 GEMM: H[N,NC] = X[N,KD] @ W[KD,NC] ----------------
// block = 256 threads, tile = 64 rows x NC cols, micro = 4 rows x (NC/16) cols

template<int NC, int KD>
__global__ __launch_bounds__(256) void gemm_kernel(const float* __restrict__ X,
                                                   const float* __restrict__ W,
                                                   float* __restrict__ Hout, int N) {
    constexpr int JC = NC / 16;
    __shared__ float As[16][68];
    __shared__ float Bs[16][NC];
    int tid = threadIdx.x;
    int i = tid & 15;    // row group: rows i*4 .. i*4+3
    int j = tid >> 4;    // col group: cols j*JC ..
    int row0 = blockIdx.x * 64;

    float acc[4][JC];
#pragma unroll
    for (int r = 0; r < 4; r++)
#pragma unroll
        for (int c = 0; c < JC; c++) acc[r][c] = 0.f;

    for (int k0 = 0; k0 < KD; k0 += 16) {
        // A tile: 64 rows x 16 k (transposed into As[k][row])
#pragma unroll
        for (int p = 0; p < 4; p++) {
            int ar = (tid >> 4) + p * 16;
            int kk = tid & 15;
            int gr = row0 + ar;
            int gk = k0 + kk;
            float v = 0.f;
            if (gr < N && gk < KD) v = X[(long)gr * KD + gk];
            As[kk][ar] = v;
        }
        // B tile: 16 k x NC cols
        for (int idx = tid; idx < 16 * NC; idx += 256) {
            int kk = idx / NC, col = idx % NC;
            int gk = k0 + kk;
            Bs[kk][col] = (gk < KD) ? W[(long)gk * NC + col] : 0.f;
        }
        __syncthreads();
#pragma unroll
        for (int kk = 0; kk < 16; kk++) {
            float a[4], b[JC];
#pragma unroll
            for (int r = 0; r < 4; r++) a[r] = As[kk][i * 4 + r];
#pragma unroll
            for (int c = 0; c < JC; c++) b[c] = Bs[kk][j * JC + c];
#pragma unroll
            for (int r = 0; r < 4; r++)
#pragma unroll
                for (int c = 0; c < JC; c++) acc[r][c] += a[r] * b[c];
        }
        __syncthreads();
    }
#pragma unroll
    for (int r = 0; r < 4; r++) {
        int gr = row0 + i * 4 + r;
        if (gr < N) {
#pragma unroll
            for (int c = 0; c < JC; c++)
                Hout[(long)gr * NC + j * JC + c] = acc[r][c];
        }
    }
}

// ---------------- attention coefficients: a_s[n,h] = sum_c h[n,h,c]*att_s[h,c] ----------------

template<int H, int C>
__global__ void att_kernel(const float* __restrict__ h, const float* __restrict__ att_s,
                           const float* __restrict__ att_d, float* __restrict__ as_,
                           float* __restrict__ ad_, int N) {
    int idx = blockIdx.x * blockDim.x + threadIdx.x;
    if (idx >= N * H) return;
    int n = idx / H, hd = idx % H;
    const float4* hp = (const float4*)(h + (long)n * H * C + hd * C);
    const float4* s4 = (const float4*)(att_s + hd * C);
    const float4* d4 = (const float4*)(att_d + hd * C);
    float ss = 0.f, dd = 0.f;
#pragma unroll
    for (int c4 = 0; c4 < C / 4; c4++) {
        float4 v = hp[c4], a = s4[c4], b = d4[c4];
        ss += v.x * a.x + v.y * a.y + v.z * a.z + v.w * a.w;
        dd += v.x * b.x + v.y * b.y + v.z * b.z + v.w * b.w;
    }
    as_[idx] = ss;
    ad_[idx] = dd;
}

// ---------------- gather layer 1: 192 threads per dst node ----------------
// out[d,t] = ELU( (sum_e ex*h[s,t]) / (sum_e ex) + bias[t] )

__global__ __launch_bounds__(192) void gather1_kernel(const int* __restrict__ rowstart,
                                                      const int* __restrict__ esrc,
                                                      const float* __restrict__ h,
                                                      const float* __restrict__ as_,
                                                      const float* __restrict__ ad_,
                                                      const float* __restrict__ bias,
                                                      float* __restrict__ xout, int N) {
    int d = blockIdx.x;
    if (d >= N) return;
    int t = threadIdx.x;       // 0..191
    int hd = t >> 4;           // head
    int beg = rowstart[d], end = rowstart[d + 1];
    float adv = ad_[d * NHEAD1 + hd];
    float accn = 0.f, accd = 0.f;
    for (int p = beg; p < end; p++) {
        int s = esrc[p];
        float ev = as_[s * NHEAD1 + hd] + adv;
        ev = ev > 0.f ? ev : NEG_SLOPE * ev;
        float ex = __expf(ev);
        accn += ex * h[(long)s * F1 + t];
        accd += ex;
    }
    float v = accn / accd + bias[t];
    xout[(long)d * F1 + t] = v > 0.f ? v : (__expf(v) - 1.f);
}

// ---------------- gather layer 2: one 64-lane wave per dst node, 4 nodes/block ----------------

__global__ __launch_bounds__(256) void gather2_kernel(const int* __restrict__ rowstart,
                                                      const int* __restrict__ esrc,
                                                      const float* __restrict__ h,
                                                      const float* __restrict__ as_,
                                                      const float* __restrict__ ad_,
                                                      const float* __restrict__ bias,
                                                      float* __restrict__ xout, int N) {
    int d = blockIdx.x * 4 + (threadIdx.x >> 6);
    if (d >= N) return;
    int t = threadIdx.x & 63;  // 0..63
    int hd = t >> 3;           // head
    int beg = rowstart[d], end = rowstart[d + 1];
    float adv = ad_[d * NHEAD2 + hd];
    float accn = 0.f, accd = 0.f;
    for (int p = beg; p < end; p++) {
        int s = esrc[p];
        float ev = as_[s * NHEAD2 + hd] + adv;
        ev = ev > 0.f ? ev : NEG_SLOPE * ev;
        float ex = __expf(ev);
        accn += ex * h[(long)s * F2 + t];
        accd += ex;
    }
    float v = accn / accd + bias[t];
    xout[(long)d * F2 + t] = v > 0.f ? v : (__expf(v) - 1.f);
}

// ---------------- pair predictor ----------------

__global__ void pair_kernel(const float* __restrict__ x, const int* __restrict__ n1,
                            const int* __restrict__ n2, const float* __restrict__ linW,
                            const float* __restrict__ linb, float* __restrict__ y, int P) {
    int idx = blockIdx.x * blockDim.x + threadIdx.x;
    if (idx >= P) return;
    const float4* xa = (const float4*)(x + (long)n1[idx] * F2);
    const float4* xb = (const float4*)(x + (long)n2[idx] * F2);
    float a0 = linb[0], a1 = linb[1];
#pragma unroll
    for (int k4 = 0; k4 < F2 / 4; k4++) {
        float4 v = xa[k4];
        int k = k4 * 4;
        a0 += v.x * linW[2 * k] + v.y * linW[2 * (k + 1)] + v.z * linW[2 * (k + 2)] + v.w * linW[2 * (k + 3)];
        a1 += v.x * linW[2 * k + 1] + v.y * linW[2 * (k + 1) + 1] + v.z * linW[2 * (k + 2) + 1] + v.w * linW[2 * (k + 3) + 1];
    }
#pragma unroll
    for (int k4 = 0; k4 < F2 / 4; k4++) {
        float4 v = xb[k4];
        int k = F2 + k4 * 4;
        a0 += v.x * linW[2 * k] + v.y * linW[2 * (k + 1)] + v.z * linW[2 * (k + 2)] + v.w * linW[2 * (k + 3)];
        a1 += v.x * linW[2 * k + 1] + v.y * linW[2 * (k + 1) + 1] + v.z * linW[2 * (k + 2) + 1] + v.w * linW[2 * (k + 3) + 1];
    }
    y[2 * idx]     = 1.f / (1.f + __expf(-a0));
    y[2 * idx + 1] = 1.f / (1.f + __expf(-a1));
}

// ---------------- launch ----------------

extern "C" void kernel_launch(void* const* d_in, const int* in_sizes, int n_in,
                              void* d_out, int out_size, void* d_ws, size_t ws_size,
                              hipStream_t stream) {
    const float* features = (const float*)d_in[0];
    const int*   ei       = (const int*)d_in[1];
    const int*   n1       = (const int*)d_in[2];
    const int*   n2       = (const int*)d_in[3];
    const float* W1       = (const float*)d_in[4];
    const float* att_s1   = (const float*)d_in[5];
    const float* att_d1   = (const float*)d_in[6];
    const float* b1       = (const float*)d_in[7];
    const float* W2       = (const float*)d_in[8];
    const float* att_s2   = (const float*)d_in[9];
    const float* att_d2   = (const float*)d_in[10];
    const float* b2       = (const float*)d_in[11];
    const float* linW     = (const float*)d_in[12];
    const float* linb     = (const float*)d_in[13];

    const int N = in_sizes[0] / NUM_FEA;      // 50000
    const int E = in_sizes[1] / 2;            // 800000
    const int P = in_sizes[2];                // 16384
    const int Etot = E + N;                   // 850000

    // workspace layout (element offsets, all 4-byte)
    float* ws = (float*)d_ws;
    long o = 0;
    float* h1  = ws + o; o += (long)N * F1;       // 9.6M
    float* x1  = ws + o; o += (long)N * F1;       // 9.6M
    float* as1 = ws + o; o += (long)N * NHEAD1;
    float* ad1 = ws + o; o += (long)N * NHEAD1;
    float* h2  = ws + o; o += (long)N * F2;
    float* as2 = ws + o; o += (long)N * NHEAD2;
    float* ad2 = ws + o; o += (long)N * NHEAD2;
    int* rowstart = (int*)(ws + o); o += N + 1;
    o = (o + 3) & ~3L;
    int* esrc = (int*)(ws + o); o += Etot;
    int* cnt  = (int*)(ws + o); o += N;
    int* cnt2 = (int*)(ws + o); o += N;

    float* y_out = (float*)d_out;             // [P,2]
    float* x_out = (float*)d_out + (long)2 * P; // [N,64]

    // zero the two counter arrays (ws is poisoned each call)
    hipMemsetAsync(cnt, 0, (size_t)2 * N * sizeof(int), stream);

    // CSR build
    deg_kernel<<<(Etot + 255) / 256, 256, 0, stream>>>(ei, cnt, E, Etot);
    scan_kernel<<<1, 1024, 0, stream>>>(cnt, rowstart, N);
    fill_kernel<<<(Etot + 255) / 256, 256, 0, stream>>>(ei, rowstart, cnt2, esrc, E, Etot);

    // layer 1
    gemm_kernel<F1, NUM_FEA><<<(N + 63) / 64, 256, 0, stream>>>(features, W1, h1, N);
    att_kernel<NHEAD1, HID1><<<(N * NHEAD1 + 255) / 256, 256, 0, stream>>>(h1, att_s1, att_d1, as1, ad1, N);
    gather1_kernel<<<N, 192, 0, stream>>>(rowstart, esrc, h1, as1, ad1, b1, x1, N);

    // layer 2
    gemm_kernel<F2, F1><<<(N + 63) / 64, 256, 0, stream>>>(x1, W2, h2, N);
    att_kernel<NHEAD2, HID2><<<(N * NHEAD2 + 255) / 256, 256, 0, stream>>>(h2, att_s2, att_d2, as2, ad2, N);
    gather2_kernel<<<(N + 3) / 4, 256, 0, stream>>>(rowstart, esrc, h2, as2, ad2, b2, x_out, N);

    // pair predictor
    pair_kernel<<<(P + 255) / 256, 256, 0, stream>>>(x_out, n1, n2, linW, linb, y_out, P);
}

// Round 2
// 611.994 us; speedup vs baseline: 1.2242x; 1.2242x over previous
//
#include <hip/hip_runtime.h>
#include <hip/hip_bf16.h>

#define HID1 16
#define NHEAD1 12
#define F1 (HID1*NHEAD1)   // 192
#define HID2 8
#define NHEAD2 8
#define F2 (HID2*NHEAD2)   // 64
#define NUM_FEA 213
#define NEG_SLOPE 0.2f
#define KP 224             // K padded to 7*32 for MFMA
#define LDK 40             // LDS k-stride (bf16 elems): 80B -> bank stride 20, 2-way max (free)
#define MROWS 128          // gemm1 block row tile

typedef __attribute__((ext_vector_type(8))) __bf16 bf16x8;
typedef __attribute__((ext_vector_type(4))) float floatx4;

static __device__ __forceinline__ unsigned short f2bf(float f) {
    unsigned u = __float_as_uint(f);
    unsigned r = (u + 0x7fffu + ((u >> 16) & 1u)) >> 16;   // RNE
    return (unsigned short)r;
}

// ---------------- CSR build ----------------

__global__ void deg_kernel(const int* __restrict__ ei, int* __restrict__ cnt, int E, int Etot) {
    int e = blockIdx.x * blockDim.x + threadIdx.x;
    if (e >= Etot) return;
    int d = (e < E) ? ei[E + e] : (e - E);
    atomicAdd(&cnt[d], 1);
}

__global__ void scan_kernel(const int* __restrict__ cnt, int* __restrict__ rowstart, int N) {
    __shared__ int carry;
    __shared__ int tmp[1024];
    int tid = threadIdx.x;
    if (tid == 0) carry = 0;
    __syncthreads();
    for (int base = 0; base < N; base += 1024) {
        int i = base + tid;
        int v = (i < N) ? cnt[i] : 0;
        tmp[tid] = v;
        __syncthreads();
        for (int off = 1; off < 1024; off <<= 1) {
            int add = (tid >= off) ? tmp[tid - off] : 0;
            __syncthreads();
            tmp[tid] += add;
            __syncthreads();
        }
        int incl = tmp[tid];
        int excl = carry + incl - v;
        if (i < N) rowstart[i] = excl;
        __syncthreads();
        if (tid == 1023) carry += incl;
        __syncthreads();
    }
    if (tid == 0) rowstart[N] = carry;
}

__global__ void fill_kernel(const int* __restrict__ ei, const int* __restrict__ rowstart,
                            int* __restrict__ cnt2, int* __restrict__ esrc, int E, int Etot) {
    int e = blockIdx.x * blockDim.x + threadIdx.x;
    if (e >= Etot) return;
    int s, d;
    if (e < E) { s = ei[e]; d = ei[E + e]; } else { s = e - E; d = s; }
    int pos = atomicAdd(&cnt2[d], 1);
    esrc[rowstart[d] + pos] = s;
}

// ---------------- bf16 conversion for GEMM1 ----------------

__global__ void convX_kernel(const float* __restrict__ X, unsigned short* __restrict__ Xbf,
                             int N, long total) {
    long idx = (long)blockIdx.x * blockDim.x + threadIdx.x;
    if (idx >= total) return;
    int r = (int)(idx / KP), k = (int)(idx % KP);
    float v = (r < N && k < NUM_FEA) ? X[(long)r * NUM_FEA + k] : 0.f;
    Xbf[idx] = f2bf(v);
}

__global__ void convW_kernel(const float* __restrict__ W, unsigned short* __restrict__ Wt) {
    int idx = blockIdx.x * blockDim.x + threadIdx.x;   // over 192*KP
    if (idx >= F1 * KP) return;
    int n = idx / KP, k = idx % KP;
    Wt[idx] = (k < NUM_FEA) ? f2bf(W[(long)k * F1 + n]) : (unsigned short)0;
}

// ---------------- GEMM1 via MFMA bf16: H[N,192] = Xbf[N,224] @ Wt^T ----------------
// block = 256 threads (4 waves), tile 128 rows x 192 cols
// wave (2x2): 64 rows x 96 cols = 4x6 subtiles of 16x16, K-chunks of 32

__global__ __launch_bounds__(256) void gemm1_mfma(const unsigned short* __restrict__ Xbf,
                                                  const unsigned short* __restrict__ Wt,
                                                  float* __restrict__ Hout, int N) {
    __shared__ unsigned short As[MROWS * LDK];   // 10.0 KB
    __shared__ unsigned short Bs[F1 * LDK];      // 15.0 KB
    int tid = threadIdx.x;
    int wave = tid >> 6, lane = tid & 63;
    int q = lane >> 4, l16 = lane & 15;
    int wm = (wave >> 1) * 64;
    int wn = (wave & 1) * 96;
    long row0 = (long)blockIdx.x * MROWS;

    floatx4 acc[4][6] = {};

    for (int k0 = 0; k0 < KP; k0 += 32) {
        // stage A: 128 rows x 32 k (2 passes, 16B per thread)
#pragma unroll
        for (int p = 0; p < 2; p++) {
            int idx = p * 256 + tid;
            int r = idx >> 2, ks = (idx & 3) * 8;
            *(int4*)&As[r * LDK + ks] = *(const int4*)&Xbf[(row0 + r) * KP + k0 + ks];
        }
        // stage B: 192 rows x 32 k (3 passes)
#pragma unroll
        for (int p = 0; p < 3; p++) {
            int idx = p * 256 + tid;
            int r = idx >> 2, ks = (idx & 3) * 8;
            *(int4*)&Bs[r * LDK + ks] = *(const int4*)&Wt[(long)r * KP + k0 + ks];
        }
        __syncthreads();
        bf16x8 af[4], bfr[6];
#pragma unroll
        for (int rt = 0; rt < 4; rt++)
            af[rt] = *(const bf16x8*)&As[(wm + rt * 16 + l16) * LDK + q * 8];
#pragma unroll
        for (int ct = 0; ct < 6; ct++)
            bfr[ct] = *(const bf16x8*)&Bs[(wn + ct * 16 + l16) * LDK + q * 8];
#pragma unroll
        for (int rt = 0; rt < 4; rt++)
#pragma unroll
            for (int ct = 0; ct < 6; ct++)
                acc[rt][ct] = __builtin_amdgcn_mfma_f32_16x16x32_bf16(af[rt], bfr[ct], acc[rt][ct], 0, 0, 0);
        __syncthreads();
    }
    // C/D layout: col = lane&15, row = (lane>>4)*4 + reg   [m89-verified]
#pragma unroll
    for (int rt = 0; rt < 4; rt++) {
#pragma unroll
        for (int r = 0; r < 4; r++) {
            long grow = row0 + wm + rt * 16 + q * 4 + r;
            if (grow < N) {
#pragma unroll
                for (int ct = 0; ct < 6; ct++)
                    Hout[grow * F1 + wn + ct * 16 + l16] = acc[rt][ct][r];
            }
        }
    }
}

// ---------------- tiled f32 GEMM (layer 2): H[N,NC] = X[N,KD] @ W[KD,NC] ----------------

template<int NC, int KD>
__global__ __launch_bounds__(256) void gemm_kernel(const float* __restrict__ X,
                                                   const float* __restrict__ W,
                                                   float* __restrict__ Hout, int N) {
    constexpr int JC = NC / 16;
    __shared__ float As[16][68];
    __shared__ float Bs[16][NC];
    int tid = threadIdx.x;
    int i = tid & 15;
    int j = tid >> 4;
    int row0 = blockIdx.x * 64;

    float acc[4][JC];
#pragma unroll
    for (int r = 0; r < 4; r++)
#pragma unroll
        for (int c = 0; c < JC; c++) acc[r][c] = 0.f;

    for (int k0 = 0; k0 < KD; k0 += 16) {
#pragma unroll
        for (int p = 0; p < 4; p++) {
            int ar = (tid >> 4) + p * 16;
            int kk = tid & 15;
            int gr = row0 + ar;
            int gk = k0 + kk;
            float v = 0.f;
            if (gr < N && gk < KD) v = X[(long)gr * KD + gk];
            As[kk][ar] = v;
        }
        for (int idx = tid; idx < 16 * NC; idx += 256) {
            int kk = idx / NC, col = idx % NC;
            int gk = k0 + kk;
            Bs[kk][col] = (gk < KD) ? W[(long)gk * NC + col] : 0.f;
        }
        __syncthreads();
#pragma unroll
        for (int kk = 0; kk < 16; kk++) {
            float a[4], b[JC];
#pragma unroll
            for (int r = 0; r < 4; r++) a[r] = As[kk][i * 4 + r];
#pragma unroll
            for (int c = 0; c < JC; c++) b[c] = Bs[kk][j * JC + c];
#pragma unroll
            for (int r = 0; r < 4; r++)
#pragma unroll
                for (int c = 0; c < JC; c++) acc[r][c] += a[r] * b[c];
        }
        __syncthreads();
    }
#pragma unroll
    for (int r = 0; r < 4; r++) {
        int gr = row0 + i * 4 + r;
        if (gr < N) {
#pragma unroll
            for (int c = 0; c < JC; c++)
                Hout[(long)gr * NC + j * JC + c] = acc[r][c];
        }
    }
}

// ---------------- attention coefficients ----------------

template<int H, int C>
__global__ void att_kernel(const float* __restrict__ h, const float* __restrict__ att_s,
                           const float* __restrict__ att_d, float* __restrict__ as_,
                           float* __restrict__ ad_, int N) {
    int idx = blockIdx.x * blockDim.x + threadIdx.x;
    if (idx >= N * H) return;
    int n = idx / H, hd = idx % H;
    const float4* hp = (const float4*)(h + (long)n * H * C + hd * C);
    const float4* s4 = (const float4*)(att_s + hd * C);
    const float4* d4 = (const float4*)(att_d + hd * C);
    float ss = 0.f, dd = 0.f;
#pragma unroll
    for (int c4 = 0; c4 < C / 4; c4++) {
        float4 v = hp[c4], a = s4[c4], b = d4[c4];
        ss += v.x * a.x + v.y * a.y + v.z * a.z + v.w * a.w;
        dd += v.x * b.x + v.y * b.y + v.z * b.z + v.w * b.w;
    }
    as_[idx] = ss;
    ad_[idx] = dd;
}

// ---------------- gather layer 1 ----------------

__global__ __launch_bounds__(192) void gather1_kernel(const int* __restrict__ rowstart,
                                                      const int* __restrict__ esrc,
                                                      const float* __restrict__ h,
                                                      const float* __restrict__ as_,
                                                      const float* __restrict__ ad_,
                                                      const float* __restrict__ bias,
                                                      float* __restrict__ xout, int N) {
    int d = blockIdx.x;
    if (d >= N) return;
    int t = threadIdx.x;
    int hd = t >> 4;
    int beg = rowstart[d], end = rowstart[d + 1];
    float adv = ad_[d * NHEAD1 + hd];
    float accn = 0.f, accd = 0.f;
    for (int p = beg; p < end; p++) {
        int s = esrc[p];
        float ev = as_[s * NHEAD1 + hd] + adv;
        ev = ev > 0.f ? ev : NEG_SLOPE * ev;
        float ex = __expf(ev);
        accn += ex * h[(long)s * F1 + t];
        accd += ex;
    }
    float v = accn / accd + bias[t];
    xout[(long)d * F1 + t] = v > 0.f ? v : (__expf(v) - 1.f);
}

// ---------------- gather layer 2 ----------------

__global__ __launch_bounds__(256) void gather2_kernel(const int* __restrict__ rowstart,
                                                      const int* __restrict__ esrc,
                                                      const float* __restrict__ h,
                                                      const float* __restrict__ as_,
                                                      const float* __restrict__ ad_,
                                                      const float* __restrict__ bias,
                                                      float* __restrict__ xout, int N) {
    int d = blockIdx.x * 4 + (threadIdx.x >> 6);
    if (d >= N) return;
    int t = threadIdx.x & 63;
    int hd = t >> 3;
    int beg = rowstart[d], end = rowstart[d + 1];
    float adv = ad_[d * NHEAD2 + hd];
    float accn = 0.f, accd = 0.f;
    for (int p = beg; p < end; p++) {
        int s = esrc[p];
        float ev = as_[s * NHEAD2 + hd] + adv;
        ev = ev > 0.f ? ev : NEG_SLOPE * ev;
        float ex = __expf(ev);
        accn += ex * h[(long)s * F2 + t];
        accd += ex;
    }
    float v = accn / accd + bias[t];
    xout[(long)d * F2 + t] = v > 0.f ? v : (__expf(v) - 1.f);
}

// ---------------- pair predictor ----------------

__global__ void pair_kernel(const float* __restrict__ x, const int* __restrict__ n1,
                            const int* __restrict__ n2, const float* __restrict__ linW,
                            const float* __restrict__ linb, float* __restrict__ y, int P) {
    int idx = blockIdx.x * blockDim.x + threadIdx.x;
    if (idx >= P) return;
    const float4* xa = (const float4*)(x + (long)n1[idx] * F2);
    const float4* xb = (const float4*)(x + (long)n2[idx] * F2);
    float a0 = linb[0], a1 = linb[1];
#pragma unroll
    for (int k4 = 0; k4 < F2 / 4; k4++) {
        float4 v = xa[k4];
        int k = k4 * 4;
        a0 += v.x * linW[2 * k] + v.y * linW[2 * (k + 1)] + v.z * linW[2 * (k + 2)] + v.w * linW[2 * (k + 3)];
        a1 += v.x * linW[2 * k + 1] + v.y * linW[2 * (k + 1) + 1] + v.z * linW[2 * (k + 2) + 1] + v.w * linW[2 * (k + 3) + 1];
    }
#pragma unroll
    for (int k4 = 0; k4 < F2 / 4; k4++) {
        float4 v = xb[k4];
        int k = F2 + k4 * 4;
        a0 += v.x * linW[2 * k] + v.y * linW[2 * (k + 1)] + v.z * linW[2 * (k + 2)] + v.w * linW[2 * (k + 3)];
        a1 += v.x * linW[2 * k + 1] + v.y * linW[2 * (k + 1) + 1] + v.z * linW[2 * (k + 2) + 1] + v.w * linW[2 * (k + 3) + 1];
    }
    y[2 * idx]     = 1.f / (1.f + __expf(-a0));
    y[2 * idx + 1] = 1.f / (1.f + __expf(-a1));
}

// ---------------- launch ----------------

extern "C" void kernel_launch(void* const* d_in, const int* in_sizes, int n_in,
                              void* d_out, int out_size, void* d_ws, size_t ws_size,
                              hipStream_t stream) {
    const float* features = (const float*)d_in[0];
    const int*   ei       = (const int*)d_in[1];
    const int*   n1       = (const int*)d_in[2];
    const int*   n2       = (const int*)d_in[3];
    const float* W1       = (const float*)d_in[4];
    const float* att_s1   = (const float*)d_in[5];
    const float* att_d1   = (const float*)d_in[6];
    const float* b1       = (const float*)d_in[7];
    const float* W2       = (const float*)d_in[8];
    const float* att_s2   = (const float*)d_in[9];
    const float* att_d2   = (const float*)d_in[10];
    const float* b2       = (const float*)d_in[11];
    const float* linW     = (const float*)d_in[12];
    const float* linb     = (const float*)d_in[13];

    const int N = in_sizes[0] / NUM_FEA;      // 50000
    const int E = in_sizes[1] / 2;            // 800000
    const int P = in_sizes[2];                // 16384
    const int Etot = E + N;                   // 850000

    const int nblk1 = (N + MROWS - 1) / MROWS;   // 391
    const int NPAD = nblk1 * MROWS;              // 50048

    float* ws = (float*)d_ws;
    long o = 0;
    float* h1  = ws + o; o += (long)N * F1;
    float* x1  = ws + o; o += (long)N * F1;      // also aliases Xbf (bf16, 50048*224 = 11.2M shorts < 9.6M floats)
    float* as1 = ws + o; o += (long)N * NHEAD1;
    float* ad1 = ws + o; o += (long)N * NHEAD1;
    float* h2  = ws + o; o += (long)N * F2;      // also aliases Wt (192*224 shorts)
    float* as2 = ws + o; o += (long)N * NHEAD2;
    float* ad2 = ws + o; o += (long)N * NHEAD2;
    int* rowstart = (int*)(ws + o); o += N + 1;
    o = (o + 3) & ~3L;
    int* esrc = (int*)(ws + o); o += Etot;
    int* cnt  = (int*)(ws + o); o += N;
    int* cnt2 = (int*)(ws + o); o += N;

    unsigned short* Xbf = (unsigned short*)x1;   // consumed before gather1 writes x1
    unsigned short* Wt  = (unsigned short*)h2;   // consumed before gemm2 writes h2

    float* y_out = (float*)d_out;
    float* x_out = (float*)d_out + (long)2 * P;

    hipMemsetAsync(cnt, 0, (size_t)2 * N * sizeof(int), stream);

    // CSR build
    deg_kernel<<<(Etot + 255) / 256, 256, 0, stream>>>(ei, cnt, E, Etot);
    scan_kernel<<<1, 1024, 0, stream>>>(cnt, rowstart, N);
    fill_kernel<<<(Etot + 255) / 256, 256, 0, stream>>>(ei, rowstart, cnt2, esrc, E, Etot);

    // layer 1: bf16 MFMA GEMM
    long totX = (long)NPAD * KP;
    convX_kernel<<<(int)((totX + 255) / 256), 256, 0, stream>>>(features, Xbf, N, totX);
    convW_kernel<<<(F1 * KP + 255) / 256, 256, 0, stream>>>(W1, Wt);
    gemm1_mfma<<<nblk1, 256, 0, stream>>>(Xbf, Wt, h1, N);
    att_kernel<NHEAD1, HID1><<<(N * NHEAD1 + 255) / 256, 256, 0, stream>>>(h1, att_s1, att_d1, as1, ad1, N);
    gather1_kernel<<<N, 192, 0, stream>>>(rowstart, esrc, h1, as1, ad1, b1, x1, N);

    // layer 2 (f32)
    gemm_kernel<F2, F1><<<(N + 63) / 64, 256, 0, stream>>>(x1, W2, h2, N);
    att_kernel<NHEAD2, HID2><<<(N * NHEAD2 + 255) / 256, 256, 0, stream>>>(h2, att_s2, att_d2, as2, ad2, N);
    gather2_kernel<<<(N + 3) / 4, 256, 0, stream>>>(rowstart, esrc, h2, as2, ad2, b2, x_out, N);

    // pair predictor
    pair_kernel<<<(P + 255) / 256, 256, 0, stream>>>(x_out, n1, n2, linW, linb, y_out, P);
}

// Round 3
// 574.273 us; speedup vs baseline: 1.3046x; 1.0657x over previous
//
#include <hip/hip_runtime.h>
#include <hip/hip_bf16.h>

#define HID1 16
#define NHEAD1 12
#define F1 (HID1*NHEAD1)   // 192
#define HID2 8
#define NHEAD2 8
#define F2 (HID2*NHEAD2)   // 64
#define NUM_FEA 213
#define NEG_SLOPE 0.2f
#define KP 224             // layer-1 K padded to 7*32 for MFMA
#define KP2 192            // layer-2 K (already 6*32)
#define LDK 40             // LDS k-stride (bf16 elems): 80B -> bank stride 20, 2-way max (free)
#define MROWS 128          // gemm block row tile

typedef __attribute__((ext_vector_type(8))) __bf16 bf16x8;
typedef __attribute__((ext_vector_type(4))) float floatx4;
typedef unsigned short ushort_t;

static __device__ __forceinline__ unsigned short f2bf(float f) {
    unsigned u = __float_as_uint(f);
    unsigned r = (u + 0x7fffu + ((u >> 16) & 1u)) >> 16;   // RNE
    return (unsigned short)r;
}
static __device__ __forceinline__ float bf2f(unsigned short u) {
    return __uint_as_float(((unsigned)u) << 16);
}

// ---------------- CSR build ----------------

__global__ void deg_kernel(const int* __restrict__ ei, int* __restrict__ cnt, int E, int Etot) {
    int e = blockIdx.x * blockDim.x + threadIdx.x;
    if (e >= Etot) return;
    int d = (e < E) ? ei[E + e] : (e - E);
    atomicAdd(&cnt[d], 1);
}

__global__ void scan_kernel(const int* __restrict__ cnt, int* __restrict__ rowstart, int N) {
    __shared__ int carry;
    __shared__ int tmp[1024];
    int tid = threadIdx.x;
    if (tid == 0) carry = 0;
    __syncthreads();
    for (int base = 0; base < N; base += 1024) {
        int i = base + tid;
        int v = (i < N) ? cnt[i] : 0;
        tmp[tid] = v;
        __syncthreads();
        for (int off = 1; off < 1024; off <<= 1) {
            int add = (tid >= off) ? tmp[tid - off] : 0;
            __syncthreads();
            tmp[tid] += add;
            __syncthreads();
        }
        int incl = tmp[tid];
        int excl = carry + incl - v;
        if (i < N) rowstart[i] = excl;
        __syncthreads();
        if (tid == 1023) carry += incl;
        __syncthreads();
    }
    if (tid == 0) rowstart[N] = carry;
}

__global__ void fill_kernel(const int* __restrict__ ei, const int* __restrict__ rowstart,
                            int* __restrict__ cnt2, int* __restrict__ esrc, int E, int Etot) {
    int e = blockIdx.x * blockDim.x + threadIdx.x;
    if (e >= Etot) return;
    int s, d;
    if (e < E) { s = ei[e]; d = ei[E + e]; } else { s = e - E; d = s; }
    int pos = atomicAdd(&cnt2[d], 1);
    esrc[rowstart[d] + pos] = s;
}

// ---------------- bf16 conversion ----------------

__global__ void convX_kernel(const float* __restrict__ X, ushort_t* __restrict__ Xbf,
                             int N, long total) {
    long idx = (long)blockIdx.x * blockDim.x + threadIdx.x;
    if (idx >= total) return;
    int r = (int)(idx / KP), k = (int)(idx % KP);
    float v = (r < N && k < NUM_FEA) ? X[(long)r * NUM_FEA + k] : 0.f;
    Xbf[idx] = f2bf(v);
}

// W[KD, NC] f32 -> Wt[NC, KPAD] bf16 (transposed, K-padded)
__global__ void convW_kernel(const float* __restrict__ W, ushort_t* __restrict__ Wt,
                             int NC, int KD, int KPAD) {
    int idx = blockIdx.x * blockDim.x + threadIdx.x;
    if (idx >= NC * KPAD) return;
    int n = idx / KPAD, k = idx % KPAD;
    Wt[idx] = (k < KD) ? f2bf(W[(long)k * NC + n]) : (ushort_t)0;
}

// ---------------- GEMM1 via MFMA bf16: h1b[N,192] = Xbf[N,224] @ Wt^T (bf16 out) ----------------
// block = 256 threads (4 waves), tile 128 rows x 192 cols
// wave (2x2): 64 rows x 96 cols = 4x6 subtiles of 16x16, K-chunks of 32

__global__ __launch_bounds__(256) void gemm1_mfma(const ushort_t* __restrict__ Xbf,
                                                  const ushort_t* __restrict__ Wt,
                                                  ushort_t* __restrict__ Hout, int N) {
    __shared__ ushort_t As[MROWS * LDK];   // 10.0 KB
    __shared__ ushort_t Bs[F1 * LDK];      // 15.0 KB
    int tid = threadIdx.x;
    int wave = tid >> 6, lane = tid & 63;
    int q = lane >> 4, l16 = lane & 15;
    int wm = (wave >> 1) * 64;
    int wn = (wave & 1) * 96;
    long row0 = (long)blockIdx.x * MROWS;

    floatx4 acc[4][6] = {};

    for (int k0 = 0; k0 < KP; k0 += 32) {
#pragma unroll
        for (int p = 0; p < 2; p++) {
            int idx = p * 256 + tid;
            int r = idx >> 2, ks = (idx & 3) * 8;
            *(int4*)&As[r * LDK + ks] = *(const int4*)&Xbf[(row0 + r) * KP + k0 + ks];
        }
#pragma unroll
        for (int p = 0; p < 3; p++) {
            int idx = p * 256 + tid;
            int r = idx >> 2, ks = (idx & 3) * 8;
            *(int4*)&Bs[r * LDK + ks] = *(const int4*)&Wt[(long)r * KP + k0 + ks];
        }
        __syncthreads();
        bf16x8 af[4], bfr[6];
#pragma unroll
        for (int rt = 0; rt < 4; rt++)
            af[rt] = *(const bf16x8*)&As[(wm + rt * 16 + l16) * LDK + q * 8];
#pragma unroll
        for (int ct = 0; ct < 6; ct++)
            bfr[ct] = *(const bf16x8*)&Bs[(wn + ct * 16 + l16) * LDK + q * 8];
#pragma unroll
        for (int rt = 0; rt < 4; rt++)
#pragma unroll
            for (int ct = 0; ct < 6; ct++)
                acc[rt][ct] = __builtin_amdgcn_mfma_f32_16x16x32_bf16(af[rt], bfr[ct], acc[rt][ct], 0, 0, 0);
        __syncthreads();
    }
    // C/D layout: col = lane&15, row = (lane>>4)*4 + reg
#pragma unroll
    for (int rt = 0; rt < 4; rt++) {
#pragma unroll
        for (int r = 0; r < 4; r++) {
            long grow = row0 + wm + rt * 16 + q * 4 + r;
            if (grow < N) {
#pragma unroll
                for (int ct = 0; ct < 6; ct++)
                    Hout[grow * F1 + wn + ct * 16 + l16] = f2bf(acc[rt][ct][r]);
            }
        }
    }
}

// ---------------- GEMM2 via MFMA bf16: h2[N,64] = x1bf[N,192] @ Wt2^T (f32 out) ----------------
// block = 256 threads (4 waves), tile 128 rows x 64 cols
// wave (2x2): 64 rows x 32 cols = 4x2 subtiles of 16x16, K-chunks of 32

__global__ __launch_bounds__(256) void gemm2_mfma(const ushort_t* __restrict__ Xbf,
                                                  const ushort_t* __restrict__ Wt,
                                                  float* __restrict__ Hout, int N) {
    __shared__ ushort_t As[MROWS * LDK];   // 10.0 KB
    __shared__ ushort_t Bs[F2 * LDK];      // 5.0 KB
    int tid = threadIdx.x;
    int wave = tid >> 6, lane = tid & 63;
    int q = lane >> 4, l16 = lane & 15;
    int wm = (wave >> 1) * 64;
    int wn = (wave & 1) * 32;
    long row0 = (long)blockIdx.x * MROWS;

    floatx4 acc[4][2] = {};

    for (int k0 = 0; k0 < KP2; k0 += 32) {
#pragma unroll
        for (int p = 0; p < 2; p++) {
            int idx = p * 256 + tid;
            int r = idx >> 2, ks = (idx & 3) * 8;
            *(int4*)&As[r * LDK + ks] = *(const int4*)&Xbf[(row0 + r) * KP2 + k0 + ks];
        }
        {
            int r = tid >> 2, ks = (tid & 3) * 8;
            if (r < F2)
                *(int4*)&Bs[r * LDK + ks] = *(const int4*)&Wt[(long)r * KP2 + k0 + ks];
        }
        __syncthreads();
        bf16x8 af[4], bfr[2];
#pragma unroll
        for (int rt = 0; rt < 4; rt++)
            af[rt] = *(const bf16x8*)&As[(wm + rt * 16 + l16) * LDK + q * 8];
#pragma unroll
        for (int ct = 0; ct < 2; ct++)
            bfr[ct] = *(const bf16x8*)&Bs[(wn + ct * 16 + l16) * LDK + q * 8];
#pragma unroll
        for (int rt = 0; rt < 4; rt++)
#pragma unroll
            for (int ct = 0; ct < 2; ct++)
                acc[rt][ct] = __builtin_amdgcn_mfma_f32_16x16x32_bf16(af[rt], bfr[ct], acc[rt][ct], 0, 0, 0);
        __syncthreads();
    }
#pragma unroll
    for (int rt = 0; rt < 4; rt++) {
#pragma unroll
        for (int r = 0; r < 4; r++) {
            long grow = row0 + wm + rt * 16 + q * 4 + r;
            if (grow < N) {
#pragma unroll
                for (int ct = 0; ct < 2; ct++)
                    Hout[grow * F2 + wn + ct * 16 + l16] = acc[rt][ct][r];
            }
        }
    }
}

// ---------------- attention coefficients (bf16 h) ----------------

template<int H, int C>
__global__ void att_bf_kernel(const ushort_t* __restrict__ h, const float* __restrict__ att_s,
                              const float* __restrict__ att_d, float* __restrict__ as_,
                              float* __restrict__ ad_, int N) {
    int idx = blockIdx.x * blockDim.x + threadIdx.x;
    if (idx >= N * H) return;
    int n = idx / H, hd = idx % H;
    const ushort_t* hp = h + (long)n * H * C + hd * C;
    const float* sp = att_s + hd * C;
    const float* dp = att_d + hd * C;
    float ss = 0.f, dd = 0.f;
#pragma unroll
    for (int c = 0; c < C; c++) {
        float v = bf2f(hp[c]);
        ss += v * sp[c];
        dd += v * dp[c];
    }
    as_[idx] = ss;
    ad_[idx] = dd;
}

// ---------------- attention coefficients (f32 h, layer 2) ----------------

template<int H, int C>
__global__ void att_kernel(const float* __restrict__ h, const float* __restrict__ att_s,
                           const float* __restrict__ att_d, float* __restrict__ as_,
                           float* __restrict__ ad_, int N) {
    int idx = blockIdx.x * blockDim.x + threadIdx.x;
    if (idx >= N * H) return;
    int n = idx / H, hd = idx % H;
    const float4* hp = (const float4*)(h + (long)n * H * C + hd * C);
    const float4* s4 = (const float4*)(att_s + hd * C);
    const float4* d4 = (const float4*)(att_d + hd * C);
    float ss = 0.f, dd = 0.f;
#pragma unroll
    for (int c4 = 0; c4 < C / 4; c4++) {
        float4 v = hp[c4], a = s4[c4], b = d4[c4];
        ss += v.x * a.x + v.y * a.y + v.z * a.z + v.w * a.w;
        dd += v.x * b.x + v.y * b.y + v.z * b.z + v.w * b.w;
    }
    as_[idx] = ss;
    ad_[idx] = dd;
}

// ---------------- gather layer 1: bf16 h in, bf16 x1 out ----------------

__global__ __launch_bounds__(192) void gather1_kernel(const int* __restrict__ rowstart,
                                                      const int* __restrict__ esrc,
                                                      const ushort_t* __restrict__ h,
                                                      const float* __restrict__ as_,
                                                      const float* __restrict__ ad_,
                                                      const float* __restrict__ bias,
                                                      ushort_t* __restrict__ xout, int N) {
    int d = blockIdx.x;
    if (d >= N) return;
    int t = threadIdx.x;
    int hd = t >> 4;
    int beg = rowstart[d], end = rowstart[d + 1];
    float adv = ad_[d * NHEAD1 + hd];
    float accn = 0.f, accd = 0.f;
    for (int p = beg; p < end; p++) {
        int s = esrc[p];
        float ev = as_[s * NHEAD1 + hd] + adv;
        ev = ev > 0.f ? ev : NEG_SLOPE * ev;
        float ex = __expf(ev);
        accn += ex * bf2f(h[(long)s * F1 + t]);
        accd += ex;
    }
    float v = accn / accd + bias[t];
    v = v > 0.f ? v : (__expf(v) - 1.f);
    xout[(long)d * F1 + t] = f2bf(v);
}

// ---------------- gather layer 2 (f32 h) ----------------

__global__ __launch_bounds__(256) void gather2_kernel(const int* __restrict__ rowstart,
                                                      const int* __restrict__ esrc,
                                                      const float* __restrict__ h,
                                                      const float* __restrict__ as_,
                                                      const float* __restrict__ ad_,
                                                      const float* __restrict__ bias,
                                                      float* __restrict__ xout, int N) {
    int d = blockIdx.x * 4 + (threadIdx.x >> 6);
    if (d >= N) return;
    int t = threadIdx.x & 63;
    int hd = t >> 3;
    int beg = rowstart[d], end = rowstart[d + 1];
    float adv = ad_[d * NHEAD2 + hd];
    float accn = 0.f, accd = 0.f;
    for (int p = beg; p < end; p++) {
        int s = esrc[p];
        float ev = as_[s * NHEAD2 + hd] + adv;
        ev = ev > 0.f ? ev : NEG_SLOPE * ev;
        float ex = __expf(ev);
        accn += ex * h[(long)s * F2 + t];
        accd += ex;
    }
    float v = accn / accd + bias[t];
    xout[(long)d * F2 + t] = v > 0.f ? v : (__expf(v) - 1.f);
}

// ---------------- pair predictor ----------------

__global__ void pair_kernel(const float* __restrict__ x, const int* __restrict__ n1,
                            const int* __restrict__ n2, const float* __restrict__ linW,
                            const float* __restrict__ linb, float* __restrict__ y, int P) {
    int idx = blockIdx.x * blockDim.x + threadIdx.x;
    if (idx >= P) return;
    const float4* xa = (const float4*)(x + (long)n1[idx] * F2);
    const float4* xb = (const float4*)(x + (long)n2[idx] * F2);
    float a0 = linb[0], a1 = linb[1];
#pragma unroll
    for (int k4 = 0; k4 < F2 / 4; k4++) {
        float4 v = xa[k4];
        int k = k4 * 4;
        a0 += v.x * linW[2 * k] + v.y * linW[2 * (k + 1)] + v.z * linW[2 * (k + 2)] + v.w * linW[2 * (k + 3)];
        a1 += v.x * linW[2 * k + 1] + v.y * linW[2 * (k + 1) + 1] + v.z * linW[2 * (k + 2) + 1] + v.w * linW[2 * (k + 3) + 1];
    }
#pragma unroll
    for (int k4 = 0; k4 < F2 / 4; k4++) {
        float4 v = xb[k4];
        int k = F2 + k4 * 4;
        a0 += v.x * linW[2 * k] + v.y * linW[2 * (k + 1)] + v.z * linW[2 * (k + 2)] + v.w * linW[2 * (k + 3)];
        a1 += v.x * linW[2 * k + 1] + v.y * linW[2 * (k + 1) + 1] + v.z * linW[2 * (k + 2) + 1] + v.w * linW[2 * (k + 3) + 1];
    }
    y[2 * idx]     = 1.f / (1.f + __expf(-a0));
    y[2 * idx + 1] = 1.f / (1.f + __expf(-a1));
}

// ---------------- launch ----------------

extern "C" void kernel_launch(void* const* d_in, const int* in_sizes, int n_in,
                              void* d_out, int out_size, void* d_ws, size_t ws_size,
                              hipStream_t stream) {
    const float* features = (const float*)d_in[0];
    const int*   ei       = (const int*)d_in[1];
    const int*   n1       = (const int*)d_in[2];
    const int*   n2       = (const int*)d_in[3];
    const float* W1       = (const float*)d_in[4];
    const float* att_s1   = (const float*)d_in[5];
    const float* att_d1   = (const float*)d_in[6];
    const float* b1       = (const float*)d_in[7];
    const float* W2       = (const float*)d_in[8];
    const float* att_s2   = (const float*)d_in[9];
    const float* att_d2   = (const float*)d_in[10];
    const float* b2       = (const float*)d_in[11];
    const float* linW     = (const float*)d_in[12];
    const float* linb     = (const float*)d_in[13];

    const int N = in_sizes[0] / NUM_FEA;      // 50000
    const int E = in_sizes[1] / 2;            // 800000
    const int P = in_sizes[2];                // 16384
    const int Etot = E + N;                   // 850000

    const int nblk = (N + MROWS - 1) / MROWS;    // 391
    const int NPAD = nblk * MROWS;               // 50048

    float* ws = (float*)d_ws;
    long o = 0;
    float* h1f  = ws + o; o += (long)N * F1;     // holds h1b (bf16, half used)
    float* x1f  = ws + o; o += (long)N * F1;     // holds Xbf (NPAD*224 bf16), then x1bf (N*192 bf16)
    float* as1 = ws + o; o += (long)N * NHEAD1;
    float* ad1 = ws + o; o += (long)N * NHEAD1;
    float* h2  = ws + o; o += (long)N * F2;      // Wt1 (bf16) lives here until gemm1 done
    float* as2 = ws + o; o += (long)N * NHEAD2;  // Wt2 (bf16) lives here until gemm2 done
    float* ad2 = ws + o; o += (long)N * NHEAD2;
    int* rowstart = (int*)(ws + o); o += N + 1;
    o = (o + 3) & ~3L;
    int* esrc = (int*)(ws + o); o += Etot;
    int* cnt  = (int*)(ws + o); o += N;
    int* cnt2 = (int*)(ws + o); o += N;

    ushort_t* h1b  = (ushort_t*)h1f;
    ushort_t* Xbf  = (ushort_t*)x1f;   // dead after gemm1
    ushort_t* x1bf = (ushort_t*)x1f;   // written by gather1 (after Xbf dead)
    ushort_t* Wt1  = (ushort_t*)h2;    // dead after gemm1; h2 written by gemm2 later
    ushort_t* Wt2  = (ushort_t*)as2;   // dead after gemm2; as2 written by att2 later

    float* y_out = (float*)d_out;
    float* x_out = (float*)d_out + (long)2 * P;

    hipMemsetAsync(cnt, 0, (size_t)2 * N * sizeof(int), stream);

    // CSR build
    deg_kernel<<<(Etot + 255) / 256, 256, 0, stream>>>(ei, cnt, E, Etot);
    scan_kernel<<<1, 1024, 0, stream>>>(cnt, rowstart, N);
    fill_kernel<<<(Etot + 255) / 256, 256, 0, stream>>>(ei, rowstart, cnt2, esrc, E, Etot);

    // layer 1: bf16 MFMA GEMM -> bf16 h1
    long totX = (long)NPAD * KP;
    convX_kernel<<<(int)((totX + 255) / 256), 256, 0, stream>>>(features, Xbf, N, totX);
    convW_kernel<<<(F1 * KP + 255) / 256, 256, 0, stream>>>(W1, Wt1, F1, NUM_FEA, KP);
    gemm1_mfma<<<nblk, 256, 0, stream>>>(Xbf, Wt1, h1b, N);
    att_bf_kernel<NHEAD1, HID1><<<(N * NHEAD1 + 255) / 256, 256, 0, stream>>>(h1b, att_s1, att_d1, as1, ad1, N);
    convW_kernel<<<(F2 * KP2 + 255) / 256, 256, 0, stream>>>(W2, Wt2, F2, F1, KP2);
    gather1_kernel<<<N, 192, 0, stream>>>(rowstart, esrc, h1b, as1, ad1, b1, x1bf, N);

    // layer 2: bf16 MFMA GEMM -> f32 h2
    gemm2_mfma<<<nblk, 256, 0, stream>>>(x1bf, Wt2, h2, N);
    att_kernel<NHEAD2, HID2><<<(N * NHEAD2 + 255) / 256, 256, 0, stream>>>(h2, att_s2, att_d2, as2, ad2, N);
    gather2_kernel<<<(N + 3) / 4, 256, 0, stream>>>(rowstart, esrc, h2, as2, ad2, b2, x_out, N);

    // pair predictor
    pair_kernel<<<(P + 255) / 256, 256, 0, stream>>>(x_out, n1, n2, linW, linb, y_out, P);
}

// Round 4
// 375.647 us; speedup vs baseline: 1.9944x; 1.5288x over previous
//
#include <hip/hip_runtime.h>
#include <hip/hip_bf16.h>

#define HID1 16
#define NHEAD1 12
#define F1 (HID1*NHEAD1)   // 192
#define HID2 8
#define NHEAD2 8
#define F2 (HID2*NHEAD2)   // 64
#define NUM_FEA 213
#define NEG_SLOPE 0.2f
#define KP 224             // layer-1 K padded to 7*32 for MFMA
#define KP2 192            // layer-2 K (already 6*32)
#define LDK 40             // LDS k-stride (bf16 elems): 80B -> bank stride 20, 2-way max (free)
#define MROWS 128          // gemm block row tile

typedef __attribute__((ext_vector_type(8))) __bf16 bf16x8;
typedef __attribute__((ext_vector_type(4))) float floatx4;
typedef unsigned short ushort_t;

static __device__ __forceinline__ unsigned short f2bf(float f) {
    unsigned u = __float_as_uint(f);
    unsigned r = (u + 0x7fffu + ((u >> 16) & 1u)) >> 16;   // RNE
    return (unsigned short)r;
}
static __device__ __forceinline__ float bf2f(unsigned short u) {
    return __uint_as_float(((unsigned)u) << 16);
}
static __device__ __forceinline__ float lrelu(float e) {
    return e > 0.f ? e : NEG_SLOPE * e;
}

// ---------------- CSR build ----------------

__global__ void deg_kernel(const int* __restrict__ ei, int* __restrict__ cnt, int E, int Etot) {
    int e = blockIdx.x * blockDim.x + threadIdx.x;
    if (e >= Etot) return;
    int d = (e < E) ? ei[E + e] : (e - E);
    atomicAdd(&cnt[d], 1);
}

// hierarchical exclusive scan: scan1 (per-256-block) -> scan2 (block sums) -> scan3 (combine)
__global__ __launch_bounds__(256) void scan1_kernel(const int* __restrict__ cnt,
                                                    int* __restrict__ part,
                                                    int* __restrict__ bsum, int N) {
    __shared__ int tmp[256];
    int tid = threadIdx.x;
    int i = blockIdx.x * 256 + tid;
    int v = (i < N) ? cnt[i] : 0;
    tmp[tid] = v;
    __syncthreads();
    for (int off = 1; off < 256; off <<= 1) {
        int add = (tid >= off) ? tmp[tid - off] : 0;
        __syncthreads();
        tmp[tid] += add;
        __syncthreads();
    }
    if (i < N) part[i] = tmp[tid] - v;       // exclusive within block
    if (tid == 255) bsum[blockIdx.x] = tmp[255];
}

__global__ __launch_bounds__(256) void scan2_kernel(int* __restrict__ bsum, int nb) {
    __shared__ int tmp[256];
    int tid = threadIdx.x;
    int v = (tid < nb) ? bsum[tid] : 0;
    tmp[tid] = v;
    __syncthreads();
    for (int off = 1; off < 256; off <<= 1) {
        int add = (tid >= off) ? tmp[tid - off] : 0;
        __syncthreads();
        tmp[tid] += add;
        __syncthreads();
    }
    if (tid < nb) bsum[tid] = tmp[tid] - v;  // exclusive
}

__global__ __launch_bounds__(256) void scan3_kernel(const int* __restrict__ part,
                                                    const int* __restrict__ bsum,
                                                    int* __restrict__ rowstart, int N, int Etot) {
    int i = blockIdx.x * 256 + threadIdx.x;
    if (i < N) rowstart[i] = part[i] + bsum[blockIdx.x];
    if (i == 0) rowstart[N] = Etot;
}

__global__ void fill_kernel(const int* __restrict__ ei, const int* __restrict__ rowstart,
                            int* __restrict__ cnt2, int* __restrict__ esrc, int E, int Etot) {
    int e = blockIdx.x * blockDim.x + threadIdx.x;
    if (e >= Etot) return;
    int s, d;
    if (e < E) { s = ei[e]; d = ei[E + e]; } else { s = e - E; d = s; }
    int pos = atomicAdd(&cnt2[d], 1);
    esrc[rowstart[d] + pos] = s;
}

// ---------------- bf16 conversion ----------------

__global__ void convX_kernel(const float* __restrict__ X, ushort_t* __restrict__ Xbf,
                             int N, long total) {
    long idx = (long)blockIdx.x * blockDim.x + threadIdx.x;
    if (idx >= total) return;
    int r = (int)(idx / KP), k = (int)(idx % KP);
    float v = (r < N && k < NUM_FEA) ? X[(long)r * NUM_FEA + k] : 0.f;
    Xbf[idx] = f2bf(v);
}

// W[KD, NC] f32 -> Wt[NC, KPAD] bf16 (transposed, K-padded)
__global__ void convW_kernel(const float* __restrict__ W, ushort_t* __restrict__ Wt,
                             int NC, int KD, int KPAD) {
    int idx = blockIdx.x * blockDim.x + threadIdx.x;
    if (idx >= NC * KPAD) return;
    int n = idx / KPAD, k = idx % KPAD;
    Wt[idx] = (k < KD) ? f2bf(W[(long)k * NC + n]) : (ushort_t)0;
}

// ---------------- GEMM1 via MFMA bf16: h1b[N,192] = Xbf[N,224] @ Wt^T (bf16 out) ----------------

__global__ __launch_bounds__(256) void gemm1_mfma(const ushort_t* __restrict__ Xbf,
                                                  const ushort_t* __restrict__ Wt,
                                                  ushort_t* __restrict__ Hout, int N) {
    __shared__ ushort_t As[MROWS * LDK];
    __shared__ ushort_t Bs[F1 * LDK];
    int tid = threadIdx.x;
    int wave = tid >> 6, lane = tid & 63;
    int q = lane >> 4, l16 = lane & 15;
    int wm = (wave >> 1) * 64;
    int wn = (wave & 1) * 96;
    long row0 = (long)blockIdx.x * MROWS;

    floatx4 acc[4][6] = {};

    for (int k0 = 0; k0 < KP; k0 += 32) {
#pragma unroll
        for (int p = 0; p < 2; p++) {
            int idx = p * 256 + tid;
            int r = idx >> 2, ks = (idx & 3) * 8;
            *(int4*)&As[r * LDK + ks] = *(const int4*)&Xbf[(row0 + r) * KP + k0 + ks];
        }
#pragma unroll
        for (int p = 0; p < 3; p++) {
            int idx = p * 256 + tid;
            int r = idx >> 2, ks = (idx & 3) * 8;
            *(int4*)&Bs[r * LDK + ks] = *(const int4*)&Wt[(long)r * KP + k0 + ks];
        }
        __syncthreads();
        bf16x8 af[4], bfr[6];
#pragma unroll
        for (int rt = 0; rt < 4; rt++)
            af[rt] = *(const bf16x8*)&As[(wm + rt * 16 + l16) * LDK + q * 8];
#pragma unroll
        for (int ct = 0; ct < 6; ct++)
            bfr[ct] = *(const bf16x8*)&Bs[(wn + ct * 16 + l16) * LDK + q * 8];
#pragma unroll
        for (int rt = 0; rt < 4; rt++)
#pragma unroll
            for (int ct = 0; ct < 6; ct++)
                acc[rt][ct] = __builtin_amdgcn_mfma_f32_16x16x32_bf16(af[rt], bfr[ct], acc[rt][ct], 0, 0, 0);
        __syncthreads();
    }
#pragma unroll
    for (int rt = 0; rt < 4; rt++) {
#pragma unroll
        for (int r = 0; r < 4; r++) {
            long grow = row0 + wm + rt * 16 + q * 4 + r;
            if (grow < N) {
#pragma unroll
                for (int ct = 0; ct < 6; ct++)
                    Hout[grow * F1 + wn + ct * 16 + l16] = f2bf(acc[rt][ct][r]);
            }
        }
    }
}

// ---------------- GEMM2 via MFMA bf16: h2b[N,64] = x1bf[N,192] @ Wt2^T (bf16 out) ----------------

__global__ __launch_bounds__(256) void gemm2_mfma(const ushort_t* __restrict__ Xbf,
                                                  const ushort_t* __restrict__ Wt,
                                                  ushort_t* __restrict__ Hout, int N) {
    __shared__ ushort_t As[MROWS * LDK];
    __shared__ ushort_t Bs[F2 * LDK];
    int tid = threadIdx.x;
    int wave = tid >> 6, lane = tid & 63;
    int q = lane >> 4, l16 = lane & 15;
    int wm = (wave >> 1) * 64;
    int wn = (wave & 1) * 32;
    long row0 = (long)blockIdx.x * MROWS;

    floatx4 acc[4][2] = {};

    for (int k0 = 0; k0 < KP2; k0 += 32) {
#pragma unroll
        for (int p = 0; p < 2; p++) {
            int idx = p * 256 + tid;
            int r = idx >> 2, ks = (idx & 3) * 8;
            *(int4*)&As[r * LDK + ks] = *(const int4*)&Xbf[(row0 + r) * KP2 + k0 + ks];
        }
        {
            int r = tid >> 2, ks = (tid & 3) * 8;
            if (r < F2)
                *(int4*)&Bs[r * LDK + ks] = *(const int4*)&Wt[(long)r * KP2 + k0 + ks];
        }
        __syncthreads();
        bf16x8 af[4], bfr[2];
#pragma unroll
        for (int rt = 0; rt < 4; rt++)
            af[rt] = *(const bf16x8*)&As[(wm + rt * 16 + l16) * LDK + q * 8];
#pragma unroll
        for (int ct = 0; ct < 2; ct++)
            bfr[ct] = *(const bf16x8*)&Bs[(wn + ct * 16 + l16) * LDK + q * 8];
#pragma unroll
        for (int rt = 0; rt < 4; rt++)
#pragma unroll
            for (int ct = 0; ct < 2; ct++)
                acc[rt][ct] = __builtin_amdgcn_mfma_f32_16x16x32_bf16(af[rt], bfr[ct], acc[rt][ct], 0, 0, 0);
        __syncthreads();
    }
#pragma unroll
    for (int rt = 0; rt < 4; rt++) {
#pragma unroll
        for (int r = 0; r < 4; r++) {
            long grow = row0 + wm + rt * 16 + q * 4 + r;
            if (grow < N) {
#pragma unroll
                for (int ct = 0; ct < 2; ct++)
                    Hout[grow * F2 + wn + ct * 16 + l16] = f2bf(acc[rt][ct][r]);
            }
        }
    }
}

// ---------------- attention coefficients (bf16 h) ----------------

template<int H, int C>
__global__ void att_bf_kernel(const ushort_t* __restrict__ h, const float* __restrict__ att_s,
                              const float* __restrict__ att_d, float* __restrict__ as_,
                              float* __restrict__ ad_, int N) {
    int idx = blockIdx.x * blockDim.x + threadIdx.x;
    if (idx >= N * H) return;
    int n = idx / H, hd = idx % H;
    const ushort_t* hp = h + (long)n * H * C + hd * C;
    const float* sp = att_s + hd * C;
    const float* dp = att_d + hd * C;
    float ss = 0.f, dd = 0.f;
#pragma unroll
    for (int c = 0; c < C; c++) {
        float v = bf2f(hp[c]);
        ss += v * sp[c];
        dd += v * dp[c];
    }
    as_[idx] = ss;
    ad_[idx] = dd;
}

// ---------------- gather layer 1: bf16 h in, bf16 x1 out, 4-way unrolled ----------------

__global__ __launch_bounds__(192) void gather1_kernel(const int* __restrict__ rowstart,
                                                      const int* __restrict__ esrc,
                                                      const ushort_t* __restrict__ h,
                                                      const float* __restrict__ as_,
                                                      const float* __restrict__ ad_,
                                                      const float* __restrict__ bias,
                                                      ushort_t* __restrict__ xout, int N) {
    int d = blockIdx.x;
    if (d >= N) return;
    int t = threadIdx.x;
    int hd = t >> 4;
    int beg = rowstart[d], end = rowstart[d + 1];
    float adv = ad_[d * NHEAD1 + hd];
    float accn = 0.f, accd = 0.f;
    int p = beg;
    for (; p + 4 <= end; p += 4) {
        int s0 = esrc[p], s1 = esrc[p + 1], s2 = esrc[p + 2], s3 = esrc[p + 3];
        float a0 = as_[s0 * NHEAD1 + hd];
        float a1 = as_[s1 * NHEAD1 + hd];
        float a2 = as_[s2 * NHEAD1 + hd];
        float a3 = as_[s3 * NHEAD1 + hd];
        float g0 = bf2f(h[(long)s0 * F1 + t]);
        float g1 = bf2f(h[(long)s1 * F1 + t]);
        float g2 = bf2f(h[(long)s2 * F1 + t]);
        float g3 = bf2f(h[(long)s3 * F1 + t]);
        float x0 = __expf(lrelu(a0 + adv));
        float x1 = __expf(lrelu(a1 + adv));
        float x2 = __expf(lrelu(a2 + adv));
        float x3 = __expf(lrelu(a3 + adv));
        accd += (x0 + x1) + (x2 + x3);
        accn += x0 * g0;
        accn += x1 * g1;
        accn += x2 * g2;
        accn += x3 * g3;
    }
    for (; p < end; p++) {
        int s = esrc[p];
        float ex = __expf(lrelu(as_[s * NHEAD1 + hd] + adv));
        accn += ex * bf2f(h[(long)s * F1 + t]);
        accd += ex;
    }
    float v = accn / accd + bias[t];
    v = v > 0.f ? v : (__expf(v) - 1.f);
    xout[(long)d * F1 + t] = f2bf(v);
}

// ---------------- gather layer 2: bf16 h in, f32 out, 4-way unrolled ----------------

__global__ __launch_bounds__(256) void gather2_kernel(const int* __restrict__ rowstart,
                                                      const int* __restrict__ esrc,
                                                      const ushort_t* __restrict__ h,
                                                      const float* __restrict__ as_,
                                                      const float* __restrict__ ad_,
                                                      const float* __restrict__ bias,
                                                      float* __restrict__ xout, int N) {
    int d = blockIdx.x * 4 + (threadIdx.x >> 6);
    if (d >= N) return;
    int t = threadIdx.x & 63;
    int hd = t >> 3;
    int beg = rowstart[d], end = rowstart[d + 1];
    float adv = ad_[d * NHEAD2 + hd];
    float accn = 0.f, accd = 0.f;
    int p = beg;
    for (; p + 4 <= end; p += 4) {
        int s0 = esrc[p], s1 = esrc[p + 1], s2 = esrc[p + 2], s3 = esrc[p + 3];
        float a0 = as_[s0 * NHEAD2 + hd];
        float a1 = as_[s1 * NHEAD2 + hd];
        float a2 = as_[s2 * NHEAD2 + hd];
        float a3 = as_[s3 * NHEAD2 + hd];
        float g0 = bf2f(h[(long)s0 * F2 + t]);
        float g1 = bf2f(h[(long)s1 * F2 + t]);
        float g2 = bf2f(h[(long)s2 * F2 + t]);
        float g3 = bf2f(h[(long)s3 * F2 + t]);
        float x0 = __expf(lrelu(a0 + adv));
        float x1 = __expf(lrelu(a1 + adv));
        float x2 = __expf(lrelu(a2 + adv));
        float x3 = __expf(lrelu(a3 + adv));
        accd += (x0 + x1) + (x2 + x3);
        accn += x0 * g0;
        accn += x1 * g1;
        accn += x2 * g2;
        accn += x3 * g3;
    }
    for (; p < end; p++) {
        int s = esrc[p];
        float ex = __expf(lrelu(as_[s * NHEAD2 + hd] + adv));
        accn += ex * bf2f(h[(long)s * F2 + t]);
        accd += ex;
    }
    float v = accn / accd + bias[t];
    xout[(long)d * F2 + t] = v > 0.f ? v : (__expf(v) - 1.f);
}

// ---------------- pair predictor ----------------

__global__ void pair_kernel(const float* __restrict__ x, const int* __restrict__ n1,
                            const int* __restrict__ n2, const float* __restrict__ linW,
                            const float* __restrict__ linb, float* __restrict__ y, int P) {
    int idx = blockIdx.x * blockDim.x + threadIdx.x;
    if (idx >= P) return;
    const float4* xa = (const float4*)(x + (long)n1[idx] * F2);
    const float4* xb = (const float4*)(x + (long)n2[idx] * F2);
    float a0 = linb[0], a1 = linb[1];
#pragma unroll
    for (int k4 = 0; k4 < F2 / 4; k4++) {
        float4 v = xa[k4];
        int k = k4 * 4;
        a0 += v.x * linW[2 * k] + v.y * linW[2 * (k + 1)] + v.z * linW[2 * (k + 2)] + v.w * linW[2 * (k + 3)];
        a1 += v.x * linW[2 * k + 1] + v.y * linW[2 * (k + 1) + 1] + v.z * linW[2 * (k + 2) + 1] + v.w * linW[2 * (k + 3) + 1];
    }
#pragma unroll
    for (int k4 = 0; k4 < F2 / 4; k4++) {
        float4 v = xb[k4];
        int k = F2 + k4 * 4;
        a0 += v.x * linW[2 * k] + v.y * linW[2 * (k + 1)] + v.z * linW[2 * (k + 2)] + v.w * linW[2 * (k + 3)];
        a1 += v.x * linW[2 * k + 1] + v.y * linW[2 * (k + 1) + 1] + v.z * linW[2 * (k + 2) + 1] + v.w * linW[2 * (k + 3) + 1];
    }
    y[2 * idx]     = 1.f / (1.f + __expf(-a0));
    y[2 * idx + 1] = 1.f / (1.f + __expf(-a1));
}

// ---------------- launch ----------------

extern "C" void kernel_launch(void* const* d_in, const int* in_sizes, int n_in,
                              void* d_out, int out_size, void* d_ws, size_t ws_size,
                              hipStream_t stream) {
    const float* features = (const float*)d_in[0];
    const int*   ei       = (const int*)d_in[1];
    const int*   n1       = (const int*)d_in[2];
    const int*   n2       = (const int*)d_in[3];
    const float* W1       = (const float*)d_in[4];
    const float* att_s1   = (const float*)d_in[5];
    const float* att_d1   = (const float*)d_in[6];
    const float* b1       = (const float*)d_in[7];
    const float* W2       = (const float*)d_in[8];
    const float* att_s2   = (const float*)d_in[9];
    const float* att_d2   = (const float*)d_in[10];
    const float* b2       = (const float*)d_in[11];
    const float* linW     = (const float*)d_in[12];
    const float* linb     = (const float*)d_in[13];

    const int N = in_sizes[0] / NUM_FEA;      // 50000
    const int E = in_sizes[1] / 2;            // 800000
    const int P = in_sizes[2];                // 16384
    const int Etot = E + N;                   // 850000

    const int nblk = (N + MROWS - 1) / MROWS;    // 391
    const int NPAD = nblk * MROWS;               // 50048
    const int nsb = (N + 255) / 256;             // scan blocks (196)

    float* ws = (float*)d_ws;
    long o = 0;
    float* h1f  = ws + o; o += (long)N * F1;     // holds h1b (bf16, half used)
    float* x1f  = ws + o; o += (long)N * F1;     // holds Xbf (NPAD*224 bf16), then x1bf (N*192 bf16)
    float* as1 = ws + o; o += (long)N * NHEAD1;
    float* ad1 = ws + o; o += (long)N * NHEAD1;
    float* h2  = ws + o; o += (long)N * F2;      // Wt1 (bf16) lives here until gemm1 done; then h2b bf16
    float* as2 = ws + o; o += (long)N * NHEAD2;  // Wt2 (bf16) lives here until gemm2 done
    float* ad2 = ws + o; o += (long)N * NHEAD2;
    int* rowstart = (int*)(ws + o); o += N + 1;
    o = (o + 3) & ~3L;
    int* esrc = (int*)(ws + o); o += Etot;
    int* cnt  = (int*)(ws + o); o += N;
    int* cnt2 = (int*)(ws + o); o += N;
    int* part = (int*)(ws + o); o += N;
    int* bsum = (int*)(ws + o); o += 256;

    ushort_t* h1b  = (ushort_t*)h1f;
    ushort_t* Xbf  = (ushort_t*)x1f;   // dead after gemm1
    ushort_t* x1bf = (ushort_t*)x1f;   // written by gather1 (after Xbf dead)
    ushort_t* Wt1  = (ushort_t*)h2;    // dead after gemm1
    ushort_t* h2b  = (ushort_t*)h2;    // written by gemm2 (after Wt1 dead)
    ushort_t* Wt2  = (ushort_t*)as2;   // dead after gemm2; as2 written by att2 later

    float* y_out = (float*)d_out;
    float* x_out = (float*)d_out + (long)2 * P;

    hipMemsetAsync(cnt, 0, (size_t)2 * N * sizeof(int), stream);

    // CSR build
    deg_kernel<<<(Etot + 255) / 256, 256, 0, stream>>>(ei, cnt, E, Etot);
    scan1_kernel<<<nsb, 256, 0, stream>>>(cnt, part, bsum, N);
    scan2_kernel<<<1, 256, 0, stream>>>(bsum, nsb);
    scan3_kernel<<<nsb, 256, 0, stream>>>(part, bsum, rowstart, N, Etot);
    fill_kernel<<<(Etot + 255) / 256, 256, 0, stream>>>(ei, rowstart, cnt2, esrc, E, Etot);

    // layer 1: bf16 MFMA GEMM -> bf16 h1
    long totX = (long)NPAD * KP;
    convX_kernel<<<(int)((totX + 255) / 256), 256, 0, stream>>>(features, Xbf, N, totX);
    convW_kernel<<<(F1 * KP + 255) / 256, 256, 0, stream>>>(W1, Wt1, F1, NUM_FEA, KP);
    gemm1_mfma<<<nblk, 256, 0, stream>>>(Xbf, Wt1, h1b, N);
    att_bf_kernel<NHEAD1, HID1><<<(N * NHEAD1 + 255) / 256, 256, 0, stream>>>(h1b, att_s1, att_d1, as1, ad1, N);
    convW_kernel<<<(F2 * KP2 + 255) / 256, 256, 0, stream>>>(W2, Wt2, F2, F1, KP2);
    gather1_kernel<<<N, 192, 0, stream>>>(rowstart, esrc, h1b, as1, ad1, b1, x1bf, N);

    // layer 2: bf16 MFMA GEMM -> bf16 h2
    gemm2_mfma<<<nblk, 256, 0, stream>>>(x1bf, Wt2, h2b, N);
    att_bf_kernel<NHEAD2, HID2><<<(N * NHEAD2 + 255) / 256, 256, 0, stream>>>(h2b, att_s2, att_d2, as2, ad2, N);
    gather2_kernel<<<(N + 3) / 4, 256, 0, stream>>>(rowstart, esrc, h2b, as2, ad2, b2, x_out, N);

    // pair predictor
    pair_kernel<<<(P + 255) / 256, 256, 0, stream>>>(x_out, n1, n2, linW, linb, y_out, P);
}